// Round 6
// baseline (605.188 us; speedup 1.0000x reference)
//
#include <hip/hip_runtime.h>

#define T_TOK 4096
#define H_DIM 2048
#define I_DIM 1408
#define E_NUM 8
#define NI2   (2 * I_DIM)   // 2816

typedef int v4i __attribute__((ext_vector_type(4)));

#define GLD_LDS16(gptr, lptr)                                                        \
  __builtin_amdgcn_global_load_lds(                                                  \
      (const __attribute__((address_space(1))) void*)(gptr),                         \
      (__attribute__((address_space(3))) void*)(lptr), 16, 0, 0)

// Recycle barrier: drain LDS-op counter THEN barrier, in ONE asm so nothing
// lands between. __syncthreads() = vmcnt(0)+lgkmcnt(0)+s_barrier; the R3/R5
// failures came from dropping the lgkmcnt(0) part: a wave could reach the raw
// s_barrier with ds_reads of the to-be-recycled buffer still in flight
// (rule #18: the consuming MFMAs + their lgkm waits are register-only and can
// sink below a "memory"-clobbered asm), so another wave's STAGE overwrote LDS
// under a pending ds_read. lgkmcnt(0) closes it; vmcnt stays counted.
#define RECYCLE_BARRIER() asm volatile("s_waitcnt lgkmcnt(0)\n\ts_barrier" ::: "memory")
#define SCHED_FENCE() __builtin_amdgcn_sched_barrier(0)

// ---------------------------------------------------------------------------
// Pack int32 -> int8 for both weight tensors in one launch
// ---------------------------------------------------------------------------
__global__ __launch_bounds__(256) void pack_all(const int* __restrict__ w13,
                                                const int* __restrict__ w2,
                                                signed char* __restrict__ qw13,
                                                signed char* __restrict__ qw2,
                                                int n16a, int n16tot) {
  int i = blockIdx.x * 256 + threadIdx.x;
  if (i >= n16tot) return;
  const int* src;
  signed char* dst;
  int j;
  if (i < n16a) { src = w13; dst = qw13; j = i; }
  else          { src = w2;  dst = qw2;  j = i - n16a; }
  const int4* s4 = (const int4*)src + (size_t)j * 4;
  int4 v0 = s4[0], v1 = s4[1], v2 = s4[2], v3 = s4[3];
  union { signed char c[16]; int4 v; } pk;
  pk.c[0] = (signed char)v0.x;  pk.c[1] = (signed char)v0.y;
  pk.c[2] = (signed char)v0.z;  pk.c[3] = (signed char)v0.w;
  pk.c[4] = (signed char)v1.x;  pk.c[5] = (signed char)v1.y;
  pk.c[6] = (signed char)v1.z;  pk.c[7] = (signed char)v1.w;
  pk.c[8] = (signed char)v2.x;  pk.c[9] = (signed char)v2.y;
  pk.c[10] = (signed char)v2.z; pk.c[11] = (signed char)v2.w;
  pk.c[12] = (signed char)v3.x; pk.c[13] = (signed char)v3.y;
  pk.c[14] = (signed char)v3.z; pk.c[15] = (signed char)v3.w;
  ((int4*)dst)[j] = pk.v;
}

// ---------------------------------------------------------------------------
// Gate logits + top-2 + dynamic int8 quant.
// ---------------------------------------------------------------------------
__global__ __launch_bounds__(256) void gate_route_quant(
    const float* __restrict__ hs, const float* __restrict__ gw,
    signed char* __restrict__ qin, float* __restrict__ s_in,
    int* __restrict__ tope, float* __restrict__ gts) {
  const int t = blockIdx.x;
  const int tid = threadIdx.x;
  const int lane = tid & 63;
  const int wave = tid >> 6;
  const float* row = hs + (size_t)t * H_DIM;

  const float4* r4 = (const float4*)row + tid * 2;
  float4 xa = r4[0], xb = r4[1];
  float x[8] = {xa.x, xa.y, xa.z, xa.w, xb.x, xb.y, xb.z, xb.w};

  double pd[8];
  for (int e = 0; e < 8; e++) pd[e] = 0.0;
  float am = 0.f;
  for (int j = 0; j < 8; j++) {
    float v = x[j];
    am = fmaxf(am, fabsf(v));
    int col = tid * 8 + j;
    for (int e = 0; e < 8; e++)
      pd[e] += (double)v * (double)gw[e * H_DIM + col];
  }
  for (int e = 0; e < 8; e++)
    for (int s = 32; s; s >>= 1) pd[e] += __shfl_down(pd[e], s);
  for (int s = 32; s; s >>= 1) am = fmaxf(am, __shfl_down(am, s));

  __shared__ double sred[4][8];
  __shared__ float sam[4];
  __shared__ float sbc;
  if (lane == 0) {
    for (int e = 0; e < 8; e++) sred[wave][e] = pd[e];
    sam[wave] = am;
  }
  __syncthreads();
  if (tid == 0) {
    float l[8];
    for (int e = 0; e < 8; e++)
      l[e] = (float)(sred[0][e] + sred[1][e] + sred[2][e] + sred[3][e]);
    float amx = fmaxf(fmaxf(sam[0], sam[1]), fmaxf(sam[2], sam[3]));
    float s = fmaxf(amx / 127.0f, 1e-8f);
    s_in[t] = s;
    sbc = s;
    int i1 = 0;
    for (int e = 1; e < 8; e++) if (l[e] > l[i1]) i1 = e;
    int i2 = -1;
    for (int e = 0; e < 8; e++) {
      if (e == i1) continue;
      if (i2 < 0 || l[e] > l[i2]) i2 = e;
    }
    float d = expf(l[i2] - l[i1]);
    tope[2 * t] = i1;     gts[2 * t] = 1.0f / (1.0f + d);
    tope[2 * t + 1] = i2; gts[2 * t + 1] = d / (1.0f + d);
  }
  __syncthreads();
  float s = sbc;
  union { signed char c[8]; unsigned long long u; } pk;
  for (int j = 0; j < 8; j++) {
    float q = rintf(x[j] / s);
    q = fminf(127.f, fmaxf(-127.f, q));
    pk.c[j] = (signed char)q;
  }
  ((unsigned long long*)(qin + (size_t)t * H_DIM))[tid] = pk.u;
}

// ---------------------------------------------------------------------------
// Build per-expert token lists with LDS atomics.
// ---------------------------------------------------------------------------
__global__ __launch_bounds__(256) void build_lists(
    const int* __restrict__ tope, int* __restrict__ tok_list,
    int* __restrict__ epos, int* __restrict__ cnt) {
  __shared__ int lc[E_NUM];
  __shared__ int lbase[E_NUM];
  const int tid = threadIdx.x;
  if (tid < E_NUM) lc[tid] = 0;
  __syncthreads();
  const int t = blockIdx.x * 256 + tid;
  int e0 = tope[2 * t], e1 = tope[2 * t + 1];
  int p0 = atomicAdd(&lc[e0], 1);
  int p1 = atomicAdd(&lc[e1], 1);
  __syncthreads();
  if (tid < E_NUM) lbase[tid] = atomicAdd(&cnt[tid], lc[tid]);
  __syncthreads();
  int pos0 = lbase[e0] + p0;
  int pos1 = lbase[e1] + p1;
  tok_list[e0 * T_TOK + pos0] = t;
  tok_list[e1 * T_TOK + pos1] = t;
  epos[2 * t] = (e0 << 16) | pos0;
  epos[2 * t + 1] = (e1 << 16) | pos1;
}

__global__ void calc_off(const int* __restrict__ cnt, int* __restrict__ off) {
  if (threadIdx.x == 0) {
    int s = 0;
    for (int e = 0; e < E_NUM; e++) { off[e] = s; s += cnt[e]; }
  }
}

// ---------------------------------------------------------------------------
// GEMM1: 64x64 tile. Counted-vmcnt pipeline (T4): 3 rotating LDS buffers,
// depth-2 prefetch. Per K-step:
//   SCHED_FENCE             (pin prev COMPUTE's MFMAs + lgkm waits here)
//   lgkmcnt(0) + s_barrier  (all waves' ds_reads of buf[stg] complete)
//   STAGE(tile kk+2 -> buf[stg])
//   s_waitcnt vmcnt(6)      (tile kk's 3 loads retired; kk+1/kk+2 in flight)
//   s_barrier               (...for ALL waves)
//   SCHED_FENCE
//   COMPUTE(tile kk)
// vmcnt never drains to 0 in-loop -> each tile's loads get ~2 K-step epochs
// to land (m218 counted-vmcnt lever). lgkm drain is cheap (~covered by the
// MFMAs behind the ds_reads) and does NOT touch the vmcnt prefetch.
// ---------------------------------------------------------------------------
__global__ __launch_bounds__(256, 4) void gemm1_silu(
    const signed char* __restrict__ qw13, const signed char* __restrict__ qin,
    const float* __restrict__ s_in, const float* __restrict__ s13,
    const int* __restrict__ tok_list, const int* __restrict__ cnt,
    const int* __restrict__ off, float* __restrict__ act,
    unsigned int* __restrict__ amax) {
  const int bid = blockIdx.x;
  const int e = bid & 7;               // expert -> XCD (round-robin %8)
  const int xt = bid >> 9;             // N tile of 64
  const int yt = (bid >> 3) & 63;      // M tile, fast within XCD
  const int ce = cnt[e];
  const int m0 = yt * 64;
  if (m0 >= ce) return;
  const int n0 = xt * 64;

  __shared__ __align__(16) signed char As[3][64 * 64];   // 12 KB
  __shared__ __align__(16) signed char Bg[3][64 * 64];   // 12 KB
  __shared__ __align__(16) signed char Bu[3][64 * 64];   // 12 KB

  const int tid = threadIdx.x;
  const int lane = tid & 63;
  const int wave = tid >> 6;
  const int quad = lane >> 4;
  const int ln = lane & 15;

  const int* tl = tok_list + e * T_TOK;
  const int rowA = tid >> 2;             // 0..63
  const int kc = (tid & 3) * 16;         // linear layout (no swizzle)

  const int tA = tl[min(m0 + rowA, ce - 1)];
  const signed char* gA = qin + (size_t)tA * H_DIM + kc;
  const signed char* w13e = qw13 + (size_t)e * NI2 * H_DIM;
  const signed char* gBg = w13e + (size_t)(n0 + rowA) * H_DIM + kc;
  const signed char* gBu = gBg + (size_t)I_DIM * H_DIM;
  const int ldsA = tid * 16;

  v4i accg[4], accu[4];
  v4i zero = {0, 0, 0, 0};
#pragma unroll
  for (int i = 0; i < 4; i++) { accg[i] = zero; accu[i] = zero; }

  auto STAGE = [&](int b, int k0) {
    GLD_LDS16(gA + k0, &As[b][ldsA]);
    GLD_LDS16(gBg + k0, &Bg[b][ldsA]);
    GLD_LDS16(gBu + k0, &Bu[b][ldsA]);
  };
  auto COMPUTE = [&](int c) {
    v4i af[4], bg, bu;
#pragma unroll
    for (int mt = 0; mt < 4; mt++)
      af[mt] = *(const v4i*)(&As[c][(mt * 16 + ln) * 64 + quad * 16]);
    bg = *(const v4i*)(&Bg[c][(wave * 16 + ln) * 64 + quad * 16]);
    bu = *(const v4i*)(&Bu[c][(wave * 16 + ln) * 64 + quad * 16]);
#pragma unroll
    for (int mt = 0; mt < 4; mt++) {
      accg[mt] = __builtin_amdgcn_mfma_i32_16x16x64_i8(af[mt], bg, accg[mt], 0, 0, 0);
      accu[mt] = __builtin_amdgcn_mfma_i32_16x16x64_i8(af[mt], bu, accu[mt], 0, 0, 0);
    }
  };

  const int NK = H_DIM / 64;   // 32
  STAGE(0, 0);
  STAGE(1, 64);
  int cur = 0, stg = 2;
  for (int kk = 0; kk < NK - 2; ++kk) {
    SCHED_FENCE();
    RECYCLE_BARRIER();                                   // lgkm(0)+barrier: buf[stg] free
    STAGE(stg, (kk + 2) * 64);
    asm volatile("s_waitcnt vmcnt(6)" ::: "memory");     // tile kk retired (this wave)
    asm volatile("s_barrier" ::: "memory");              // ...for ALL waves
    SCHED_FENCE();
    COMPUTE(cur);
    cur = (cur == 2) ? 0 : cur + 1;
    stg = (stg == 2) ? 0 : stg + 1;
  }
  SCHED_FENCE();
  asm volatile("s_waitcnt vmcnt(3)" ::: "memory");
  asm volatile("s_barrier" ::: "memory");
  SCHED_FENCE();
  COMPUTE(cur);
  cur = (cur == 2) ? 0 : cur + 1;
  SCHED_FENCE();
  asm volatile("s_waitcnt vmcnt(0)" ::: "memory");
  asm volatile("s_barrier" ::: "memory");
  SCHED_FENCE();
  COMPUTE(cur);

  const float* s13e = s13 + e * NI2;
  const int n = n0 + wave * 16 + ln;
  const float sgv = s13e[n];
  const float suv = s13e[I_DIM + n];
  const int offe = off[e];
#pragma unroll
  for (int mt = 0; mt < 4; mt++) {
#pragma unroll
    for (int r = 0; r < 4; r++) {
      int mrel = m0 + mt * 16 + quad * 4 + r;
      bool valid = mrel < ce;
      int tok = tl[valid ? mrel : 0];
      float si = s_in[tok];
      int crow = offe + mrel;
      float g = (float)accg[mt][r] * si * sgv;
      float u = (float)accu[mt][r] * si * suv;
      float a = g / (1.0f + expf(-g)) * u;
      if (valid) act[(size_t)crow * I_DIM + n] = a;
      float am = fabsf(a);
      for (int s = 1; s < 16; s <<= 1) am = fmaxf(am, __shfl_xor(am, s, 16));
      if (valid && ln == 0) atomicMax(amax + crow, __float_as_uint(am));
    }
  }
}

// ---------------------------------------------------------------------------
// Per-row dynamic int8 quant of act
// ---------------------------------------------------------------------------
__global__ __launch_bounds__(256) void quant_act(const float* __restrict__ act,
                                                 const unsigned int* __restrict__ amax,
                                                 signed char* __restrict__ qa,
                                                 float* __restrict__ s_a) {
  const int r = blockIdx.x;
  float am = __uint_as_float(amax[r]);
  float s = fmaxf(am / 127.0f, 1e-8f);
  if (threadIdx.x == 0) s_a[r] = s;
  const float* arow = act + (size_t)r * I_DIM;
  signed char* qrow = qa + (size_t)r * I_DIM;
  for (int j = threadIdx.x; j < I_DIM; j += 256) {
    float q = rintf(arow[j] / s);
    q = fminf(127.f, fmaxf(-127.f, q));
    qrow[j] = (signed char)q;
  }
}

// ---------------------------------------------------------------------------
// GEMM2: 64x128 tile, same fenced counted-vmcnt pipeline + XCD decode.
// 3 loads/thread/tile -> vmcnt(6)/3/0.
// ---------------------------------------------------------------------------
__global__ __launch_bounds__(256, 4) void gemm2_h2(
    const signed char* __restrict__ qw2, const signed char* __restrict__ qa,
    const float* __restrict__ s_a, const float* __restrict__ s2w,
    const int* __restrict__ cnt, const int* __restrict__ off,
    float* __restrict__ h2s) {
  const int bid = blockIdx.x;
  const int e = bid & 7;               // expert -> XCD
  const int xt = bid >> 9;             // N tile of 128
  const int yt = (bid >> 3) & 63;      // M tile
  const int ce = cnt[e];
  const int m0 = yt * 64;
  if (m0 >= ce) return;
  const int n0 = xt * 128;
  const int offe = off[e];

  __shared__ __align__(16) signed char As[3][64 * 64];    // 12 KB
  __shared__ __align__(16) signed char Bs[3][128 * 64];   // 24 KB

  const int tid = threadIdx.x;
  const int lane = tid & 63;
  const int wave = tid >> 6;
  const int quad = lane >> 4;
  const int ln = lane & 15;

  const int rowA = tid >> 2;
  const int kc = (tid & 3) * 16;

  const signed char* gA = qa + (size_t)(offe + min(m0 + rowA, ce - 1)) * I_DIM + kc;
  const signed char* w2e = qw2 + (size_t)e * H_DIM * I_DIM;
  const signed char* gB0 = w2e + (size_t)(n0 + rowA) * I_DIM + kc;
  const signed char* gB1 = gB0 + (size_t)64 * I_DIM;
  const int ldsA = tid * 16;

  v4i acc[4][2];
  v4i zero = {0, 0, 0, 0};
#pragma unroll
  for (int i = 0; i < 4; i++)
#pragma unroll
    for (int j = 0; j < 2; j++) acc[i][j] = zero;

  auto STAGE = [&](int b, int k0) {
    GLD_LDS16(gA + k0, &As[b][ldsA]);
    GLD_LDS16(gB0 + k0, &Bs[b][ldsA]);
    GLD_LDS16(gB1 + k0, &Bs[b][4096 + ldsA]);
  };
  auto COMPUTE = [&](int c) {
    v4i af[4], bf[2];
#pragma unroll
    for (int mt = 0; mt < 4; mt++)
      af[mt] = *(const v4i*)(&As[c][(mt * 16 + ln) * 64 + quad * 16]);
#pragma unroll
    for (int nt = 0; nt < 2; nt++)
      bf[nt] = *(const v4i*)(&Bs[c][(wave * 32 + nt * 16 + ln) * 64 + quad * 16]);
#pragma unroll
    for (int mt = 0; mt < 4; mt++)
#pragma unroll
      for (int nt = 0; nt < 2; nt++)
        acc[mt][nt] = __builtin_amdgcn_mfma_i32_16x16x64_i8(af[mt], bf[nt], acc[mt][nt], 0, 0, 0);
  };

  const int NK = I_DIM / 64;   // 22
  STAGE(0, 0);
  STAGE(1, 64);
  int cur = 0, stg = 2;
  for (int kk = 0; kk < NK - 2; ++kk) {
    SCHED_FENCE();
    RECYCLE_BARRIER();
    STAGE(stg, (kk + 2) * 64);
    asm volatile("s_waitcnt vmcnt(6)" ::: "memory");
    asm volatile("s_barrier" ::: "memory");
    SCHED_FENCE();
    COMPUTE(cur);
    cur = (cur == 2) ? 0 : cur + 1;
    stg = (stg == 2) ? 0 : stg + 1;
  }
  SCHED_FENCE();
  asm volatile("s_waitcnt vmcnt(3)" ::: "memory");
  asm volatile("s_barrier" ::: "memory");
  SCHED_FENCE();
  COMPUTE(cur);
  cur = (cur == 2) ? 0 : cur + 1;
  SCHED_FENCE();
  asm volatile("s_waitcnt vmcnt(0)" ::: "memory");
  asm volatile("s_barrier" ::: "memory");
  SCHED_FENCE();
  COMPUTE(cur);

  const float* s2e = s2w + e * H_DIM;
  float sw[2];
  int ncol[2];
#pragma unroll
  for (int nt = 0; nt < 2; nt++) {
    int n = n0 + wave * 32 + nt * 16 + ln;
    ncol[nt] = n;
    sw[nt] = s2e[n];
  }
#pragma unroll
  for (int mt = 0; mt < 4; mt++) {
#pragma unroll
    for (int r = 0; r < 4; r++) {
      int mrel = m0 + mt * 16 + quad * 4 + r;
      if (mrel >= ce) continue;
      float sa = s_a[offe + mrel];
      float* orow = h2s + (size_t)(offe + mrel) * H_DIM;
#pragma unroll
      for (int nt = 0; nt < 2; nt++)
        orow[ncol[nt]] = (float)acc[mt][nt][r] * sa * sw[nt];
    }
  }
}

// ---------------------------------------------------------------------------
// Final gather: out[t] = g1 * h2s[r1] + g2 * h2s[r2]
// ---------------------------------------------------------------------------
__global__ __launch_bounds__(256) void gather_out(
    const float* __restrict__ h2s, const int* __restrict__ epos,
    const float* __restrict__ gts, const int* __restrict__ off,
    float* __restrict__ out) {
  const int t = blockIdx.x;
  int a = epos[2 * t], b = epos[2 * t + 1];
  float g1 = gts[2 * t], g2 = gts[2 * t + 1];
  int r1 = off[a >> 16] + (a & 0xffff);
  int r2 = off[b >> 16] + (b & 0xffff);
  const float4* R1 = (const float4*)(h2s + (size_t)r1 * H_DIM);
  const float4* R2 = (const float4*)(h2s + (size_t)r2 * H_DIM);
  float4* O = (float4*)(out + (size_t)t * H_DIM);
  for (int c = threadIdx.x; c < H_DIM / 4; c += 256) {
    float4 x = R1[c], y = R2[c];
    float4 z;
    z.x = g1 * x.x + g2 * y.x;
    z.y = g1 * x.y + g2 * y.y;
    z.z = g1 * x.z + g2 * y.z;
    z.w = g1 * x.w + g2 * y.w;
    O[c] = z;
  }
}

// ---------------------------------------------------------------------------
extern "C" void kernel_launch(void* const* d_in, const int* in_sizes, int n_in,
                              void* d_out, int out_size, void* d_ws, size_t ws_size,
                              hipStream_t stream) {
  const float* hs = (const float*)d_in[0];
  const float* gw = (const float*)d_in[1];
  const int* w13 = (const int*)d_in[2];
  const float* s13 = (const float*)d_in[3];
  const int* w2 = (const int*)d_in[4];
  const float* s2w = (const float*)d_in[5];
  float* out = (float*)d_out;

  char* ws = (char*)d_ws;
  size_t o = 0;
  auto take = [&](size_t b) {
    char* p = ws + o;
    o += (b + 255) & ~(size_t)255;
    return p;
  };
  signed char* qw13 = (signed char*)take((size_t)E_NUM * NI2 * H_DIM);       // 46.1 MB
  signed char* qin = (signed char*)take((size_t)T_TOK * H_DIM);              // 8.4 MB
  float* act = (float*)take((size_t)T_TOK * 2 * I_DIM * 4);                  // 46.1 MB
  float* h2s = (float*)qw13;  // aliases dead qw13+qin+act space (67.1 MB needed)
  signed char* qw2 = (signed char*)take((size_t)E_NUM * H_DIM * I_DIM);      // 23.1 MB
  signed char* qa = (signed char*)take((size_t)T_TOK * 2 * I_DIM);           // 11.5 MB
  float* sin_ = (float*)take((size_t)T_TOK * 4);
  float* sa = (float*)take((size_t)T_TOK * 2 * 4);
  unsigned int* amax = (unsigned int*)take((size_t)T_TOK * 2 * 4);
  int* tokl = (int*)take((size_t)E_NUM * T_TOK * 4);
  int* tope = (int*)take((size_t)T_TOK * 2 * 4);
  int* epos = (int*)take((size_t)T_TOK * 2 * 4);
  float* gts = (float*)take((size_t)T_TOK * 2 * 4);
  int* cnt = (int*)take(E_NUM * 4);
  int* off = (int*)take(E_NUM * 4);

  hipMemsetAsync(amax, 0, (size_t)T_TOK * 2 * 4, stream);
  hipMemsetAsync(cnt, 0, (size_t)E_NUM * 4, stream);

  {
    int n16a = E_NUM * NI2 * H_DIM / 16;
    int n16b = E_NUM * H_DIM * I_DIM / 16;
    int n16tot = n16a + n16b;
    pack_all<<<(n16tot + 255) / 256, 256, 0, stream>>>(w13, w2, qw13, qw2, n16a, n16tot);
  }
  gate_route_quant<<<T_TOK, 256, 0, stream>>>(hs, gw, qin, sin_, tope, gts);
  build_lists<<<T_TOK / 256, 256, 0, stream>>>(tope, tokl, epos, cnt);
  calc_off<<<1, 64, 0, stream>>>(cnt, off);
  // 1-D grids: bid = ((xt*64)+yt)*8 + e  (expert = bid&7 -> XCD affinity)
  gemm1_silu<<<(I_DIM / 64) * 64 * E_NUM, 256, 0, stream>>>(qw13, qin, sin_, s13, tokl, cnt, off, act, amax);
  quant_act<<<T_TOK * 2, 256, 0, stream>>>(act, amax, qa, sa);
  gemm2_h2<<<(H_DIM / 128) * 64 * E_NUM, 256, 0, stream>>>(qw2, qa, sa, s2w, cnt, off, h2s);
  gather_out<<<T_TOK, 256, 0, stream>>>(h2s, epos, gts, off, out);
}

// Round 7
// 563.226 us; speedup vs baseline: 1.0745x; 1.0745x over previous
//
#include <hip/hip_runtime.h>

#define T_TOK 4096
#define H_DIM 2048
#define I_DIM 1408
#define E_NUM 8
#define NI2   (2 * I_DIM)   // 2816

typedef int v4i __attribute__((ext_vector_type(4)));

#define GLD_LDS16(gptr, lptr)                                                        \
  __builtin_amdgcn_global_load_lds(                                                  \
      (const __attribute__((address_space(1))) void*)(gptr),                         \
      (__attribute__((address_space(3))) void*)(lptr), 16, 0, 0)

// ---------------------------------------------------------------------------
// Pack int32 -> int8 for both weight tensors in one launch
// ---------------------------------------------------------------------------
__global__ __launch_bounds__(256) void pack_all(const int* __restrict__ w13,
                                                const int* __restrict__ w2,
                                                signed char* __restrict__ qw13,
                                                signed char* __restrict__ qw2,
                                                int n16a, int n16tot) {
  int i = blockIdx.x * 256 + threadIdx.x;
  if (i >= n16tot) return;
  const int* src;
  signed char* dst;
  int j;
  if (i < n16a) { src = w13; dst = qw13; j = i; }
  else          { src = w2;  dst = qw2;  j = i - n16a; }
  const int4* s4 = (const int4*)src + (size_t)j * 4;
  int4 v0 = s4[0], v1 = s4[1], v2 = s4[2], v3 = s4[3];
  union { signed char c[16]; int4 v; } pk;
  pk.c[0] = (signed char)v0.x;  pk.c[1] = (signed char)v0.y;
  pk.c[2] = (signed char)v0.z;  pk.c[3] = (signed char)v0.w;
  pk.c[4] = (signed char)v1.x;  pk.c[5] = (signed char)v1.y;
  pk.c[6] = (signed char)v1.z;  pk.c[7] = (signed char)v1.w;
  pk.c[8] = (signed char)v2.x;  pk.c[9] = (signed char)v2.y;
  pk.c[10] = (signed char)v2.z; pk.c[11] = (signed char)v2.w;
  pk.c[12] = (signed char)v3.x; pk.c[13] = (signed char)v3.y;
  pk.c[14] = (signed char)v3.z; pk.c[15] = (signed char)v3.w;
  ((int4*)dst)[j] = pk.v;
}

// ---------------------------------------------------------------------------
// Gate logits + top-2 + dynamic int8 quant.
// ---------------------------------------------------------------------------
__global__ __launch_bounds__(256) void gate_route_quant(
    const float* __restrict__ hs, const float* __restrict__ gw,
    signed char* __restrict__ qin, float* __restrict__ s_in,
    int* __restrict__ tope, float* __restrict__ gts) {
  const int t = blockIdx.x;
  const int tid = threadIdx.x;
  const int lane = tid & 63;
  const int wave = tid >> 6;
  const float* row = hs + (size_t)t * H_DIM;

  const float4* r4 = (const float4*)row + tid * 2;
  float4 xa = r4[0], xb = r4[1];
  float x[8] = {xa.x, xa.y, xa.z, xa.w, xb.x, xb.y, xb.z, xb.w};

  double pd[8];
  for (int e = 0; e < 8; e++) pd[e] = 0.0;
  float am = 0.f;
  for (int j = 0; j < 8; j++) {
    float v = x[j];
    am = fmaxf(am, fabsf(v));
    int col = tid * 8 + j;
    for (int e = 0; e < 8; e++)
      pd[e] += (double)v * (double)gw[e * H_DIM + col];
  }
  for (int e = 0; e < 8; e++)
    for (int s = 32; s; s >>= 1) pd[e] += __shfl_down(pd[e], s);
  for (int s = 32; s; s >>= 1) am = fmaxf(am, __shfl_down(am, s));

  __shared__ double sred[4][8];
  __shared__ float sam[4];
  __shared__ float sbc;
  if (lane == 0) {
    for (int e = 0; e < 8; e++) sred[wave][e] = pd[e];
    sam[wave] = am;
  }
  __syncthreads();
  if (tid == 0) {
    float l[8];
    for (int e = 0; e < 8; e++)
      l[e] = (float)(sred[0][e] + sred[1][e] + sred[2][e] + sred[3][e]);
    float amx = fmaxf(fmaxf(sam[0], sam[1]), fmaxf(sam[2], sam[3]));
    float s = fmaxf(amx / 127.0f, 1e-8f);
    s_in[t] = s;
    sbc = s;
    int i1 = 0;
    for (int e = 1; e < 8; e++) if (l[e] > l[i1]) i1 = e;
    int i2 = -1;
    for (int e = 0; e < 8; e++) {
      if (e == i1) continue;
      if (i2 < 0 || l[e] > l[i2]) i2 = e;
    }
    float d = expf(l[i2] - l[i1]);
    tope[2 * t] = i1;     gts[2 * t] = 1.0f / (1.0f + d);
    tope[2 * t + 1] = i2; gts[2 * t + 1] = d / (1.0f + d);
  }
  __syncthreads();
  float s = sbc;
  union { signed char c[8]; unsigned long long u; } pk;
  for (int j = 0; j < 8; j++) {
    float q = rintf(x[j] / s);
    q = fminf(127.f, fmaxf(-127.f, q));
    pk.c[j] = (signed char)q;
  }
  ((unsigned long long*)(qin + (size_t)t * H_DIM))[tid] = pk.u;
}

// ---------------------------------------------------------------------------
// Build per-expert token lists with LDS atomics.
// ---------------------------------------------------------------------------
__global__ __launch_bounds__(256) void build_lists(
    const int* __restrict__ tope, int* __restrict__ tok_list,
    int* __restrict__ epos, int* __restrict__ cnt) {
  __shared__ int lc[E_NUM];
  __shared__ int lbase[E_NUM];
  const int tid = threadIdx.x;
  if (tid < E_NUM) lc[tid] = 0;
  __syncthreads();
  const int t = blockIdx.x * 256 + tid;
  int e0 = tope[2 * t], e1 = tope[2 * t + 1];
  int p0 = atomicAdd(&lc[e0], 1);
  int p1 = atomicAdd(&lc[e1], 1);
  __syncthreads();
  if (tid < E_NUM) lbase[tid] = atomicAdd(&cnt[tid], lc[tid]);
  __syncthreads();
  int pos0 = lbase[e0] + p0;
  int pos1 = lbase[e1] + p1;
  tok_list[e0 * T_TOK + pos0] = t;
  tok_list[e1 * T_TOK + pos1] = t;
  epos[2 * t] = (e0 << 16) | pos0;
  epos[2 * t + 1] = (e1 << 16) | pos1;
}

__global__ void calc_off(const int* __restrict__ cnt, int* __restrict__ off) {
  if (threadIdx.x == 0) {
    int s = 0;
    for (int e = 0; e < E_NUM; e++) { off[e] = s; s += cnt[e]; }
  }
}

// ---------------------------------------------------------------------------
// GEMM1: 128x64 tile (128 tokens x 64 cols of BOTH g and u). The R2/R6
// counters fit an L2-BANDWIDTH bound (staged bytes / 34.5 TB/s = measured
// dur within 10%): 64x64 tiles pulled 4.3 GB through L2. This tile stages
// (A 8KB + W 8KB)/K-step over 1408 active blocks = 0.72 GB (6x cut),
// putting the L2 floor (~21us) under the MFMA floor (~24us).
// Wave layout: 4 waves = 4 M-bands of 32 rows; per wave 2 m-frags x 4 n-frags
// x {g,u} = 16 v4i acc = 64 AGPR (proven R0 count). ~150 regs -> 2 blocks/CU;
// low occupancy is fine: traffic, not latency, was binding.
// Loop = byte-for-byte proven R2/R4 serial two-barrier skeleton (no asm).
// 1-D grid, expert = bid&7 -> XCD affinity (verified: FETCH 267->42 MB).
// ---------------------------------------------------------------------------
__global__ __launch_bounds__(256, 2) void gemm1_silu(
    const signed char* __restrict__ qw13, const signed char* __restrict__ qin,
    const float* __restrict__ s_in, const float* __restrict__ s13,
    const int* __restrict__ tok_list, const int* __restrict__ cnt,
    const int* __restrict__ off, float* __restrict__ act,
    unsigned int* __restrict__ amax) {
  const int bid = blockIdx.x;
  const int e = bid & 7;               // expert -> XCD (round-robin %8)
  const int yt = (bid >> 3) & 31;      // M tile of 128 (fast within XCD)
  const int xt = bid >> 8;             // N tile of 64 (0..21)
  const int ce = cnt[e];
  const int m0 = yt * 128;
  if (m0 >= ce) return;
  const int n0 = xt * 64;

  __shared__ __align__(16) signed char As[128 * 64];   // 8 KB
  __shared__ __align__(16) signed char Bg[64 * 64];    // 4 KB
  __shared__ __align__(16) signed char Bu[64 * 64];    // 4 KB

  const int tid = threadIdx.x;
  const int lane = tid & 63;
  const int wave = tid >> 6;
  const int quad = lane >> 4;
  const int ln = lane & 15;

  const int* tl = tok_list + e * T_TOK;
  const int rowA = tid >> 2;             // 0..63
  const int kc = (tid & 3) * 16;

  const int tA0 = tl[min(m0 + rowA, ce - 1)];
  const int tA1 = tl[min(m0 + 64 + rowA, ce - 1)];
  const signed char* gA0 = qin + (size_t)tA0 * H_DIM + kc;
  const signed char* gA1 = qin + (size_t)tA1 * H_DIM + kc;
  const signed char* w13e = qw13 + (size_t)e * NI2 * H_DIM;
  const signed char* gBg = w13e + (size_t)(n0 + rowA) * H_DIM + kc;
  const signed char* gBu = gBg + (size_t)I_DIM * H_DIM;
  const int ldsA = tid * 16;

  v4i accg[2][4], accu[2][4];
  v4i zero = {0, 0, 0, 0};
#pragma unroll
  for (int i = 0; i < 2; i++)
#pragma unroll
    for (int j = 0; j < 4; j++) { accg[i][j] = zero; accu[i][j] = zero; }

  for (int k0 = 0; k0 < H_DIM; k0 += 64) {
    __syncthreads();
    GLD_LDS16(gA0 + k0, As + ldsA);
    GLD_LDS16(gA1 + k0, As + 4096 + ldsA);
    GLD_LDS16(gBg + k0, Bg + ldsA);
    GLD_LDS16(gBu + k0, Bu + ldsA);
    __syncthreads();

    v4i af[2], bg[4], bu[4];
#pragma unroll
    for (int mt = 0; mt < 2; mt++)
      af[mt] = *(const v4i*)(As + (wave * 32 + mt * 16 + ln) * 64 + quad * 16);
#pragma unroll
    for (int nf = 0; nf < 4; nf++) {
      bg[nf] = *(const v4i*)(Bg + (nf * 16 + ln) * 64 + quad * 16);
      bu[nf] = *(const v4i*)(Bu + (nf * 16 + ln) * 64 + quad * 16);
    }
#pragma unroll
    for (int mt = 0; mt < 2; mt++)
#pragma unroll
      for (int nf = 0; nf < 4; nf++) {
        accg[mt][nf] = __builtin_amdgcn_mfma_i32_16x16x64_i8(af[mt], bg[nf], accg[mt][nf], 0, 0, 0);
        accu[mt][nf] = __builtin_amdgcn_mfma_i32_16x16x64_i8(af[mt], bu[nf], accu[mt][nf], 0, 0, 0);
      }
  }

  const float* s13e = s13 + e * NI2;
  float sg[4], su[4];
  int ncol[4];
#pragma unroll
  for (int nf = 0; nf < 4; nf++) {
    int n = n0 + nf * 16 + ln;
    ncol[nf] = n;
    sg[nf] = s13e[n];
    su[nf] = s13e[I_DIM + n];
  }
  const int offe = off[e];
#pragma unroll
  for (int mt = 0; mt < 2; mt++) {
#pragma unroll
    for (int r = 0; r < 4; r++) {
      int mrel = m0 + wave * 32 + mt * 16 + quad * 4 + r;
      bool valid = mrel < ce;
      int tok = tl[valid ? mrel : 0];
      float si = s_in[tok];
      int crow = offe + mrel;
      float* arow = act + (size_t)crow * I_DIM;
      float am = 0.f;
#pragma unroll
      for (int nf = 0; nf < 4; nf++) {
        float g = (float)accg[mt][nf][r] * si * sg[nf];
        float u = (float)accu[mt][nf][r] * si * su[nf];
        float a = g / (1.0f + expf(-g)) * u;
        if (valid) arow[ncol[nf]] = a;
        am = fmaxf(am, fabsf(a));
      }
      for (int s = 1; s < 16; s <<= 1) am = fmaxf(am, __shfl_xor(am, s, 16));
      if (valid && ln == 0) atomicMax(amax + crow, __float_as_uint(am));
    }
  }
}

// ---------------------------------------------------------------------------
// Per-row dynamic int8 quant of act
// ---------------------------------------------------------------------------
__global__ __launch_bounds__(256) void quant_act(const float* __restrict__ act,
                                                 const unsigned int* __restrict__ amax,
                                                 signed char* __restrict__ qa,
                                                 float* __restrict__ s_a) {
  const int r = blockIdx.x;
  float am = __uint_as_float(amax[r]);
  float s = fmaxf(am / 127.0f, 1e-8f);
  if (threadIdx.x == 0) s_a[r] = s;
  const float* arow = act + (size_t)r * I_DIM;
  signed char* qrow = qa + (size_t)r * I_DIM;
  for (int j = threadIdx.x; j < I_DIM; j += 256) {
    float q = rintf(arow[j] / s);
    q = fminf(127.f, fmaxf(-127.f, q));
    qrow[j] = (signed char)q;
  }
}

// ---------------------------------------------------------------------------
// GEMM2: 128x128 tile, same serial two-barrier skeleton + XCD decode.
// Staged traffic (A 8KB + B 8KB)/K-step over ~1024 active blocks = 360 MB
// (4x cut vs the 64x128 version). acc 2x8 = 64 AGPR/wave.
// ---------------------------------------------------------------------------
__global__ __launch_bounds__(256, 2) void gemm2_h2(
    const signed char* __restrict__ qw2, const signed char* __restrict__ qa,
    const float* __restrict__ s_a, const float* __restrict__ s2w,
    const int* __restrict__ cnt, const int* __restrict__ off,
    float* __restrict__ h2s) {
  const int bid = blockIdx.x;
  const int e = bid & 7;               // expert -> XCD
  const int yt = (bid >> 3) & 31;      // M tile of 128
  const int xt = bid >> 8;             // N tile of 128 (0..15)
  const int ce = cnt[e];
  const int m0 = yt * 128;
  if (m0 >= ce) return;
  const int n0 = xt * 128;
  const int offe = off[e];

  __shared__ __align__(16) signed char As[128 * 64];   // 8 KB
  __shared__ __align__(16) signed char Bs[128 * 64];   // 8 KB

  const int tid = threadIdx.x;
  const int lane = tid & 63;
  const int wave = tid >> 6;
  const int quad = lane >> 4;
  const int ln = lane & 15;

  const int rowA = tid >> 2;
  const int kc = (tid & 3) * 16;

  const signed char* gA0 = qa + (size_t)(offe + min(m0 + rowA, ce - 1)) * I_DIM + kc;
  const signed char* gA1 = qa + (size_t)(offe + min(m0 + 64 + rowA, ce - 1)) * I_DIM + kc;
  const signed char* w2e = qw2 + (size_t)e * H_DIM * I_DIM;
  const signed char* gB0 = w2e + (size_t)(n0 + rowA) * I_DIM + kc;
  const signed char* gB1 = gB0 + (size_t)64 * I_DIM;
  const int ldsA = tid * 16;

  v4i acc[2][8];
  v4i zero = {0, 0, 0, 0};
#pragma unroll
  for (int i = 0; i < 2; i++)
#pragma unroll
    for (int j = 0; j < 8; j++) acc[i][j] = zero;

  for (int k0 = 0; k0 < I_DIM; k0 += 64) {
    __syncthreads();
    GLD_LDS16(gA0 + k0, As + ldsA);
    GLD_LDS16(gA1 + k0, As + 4096 + ldsA);
    GLD_LDS16(gB0 + k0, Bs + ldsA);
    GLD_LDS16(gB1 + k0, Bs + 4096 + ldsA);
    __syncthreads();

    v4i af[2], bf[8];
#pragma unroll
    for (int mt = 0; mt < 2; mt++)
      af[mt] = *(const v4i*)(As + (wave * 32 + mt * 16 + ln) * 64 + quad * 16);
#pragma unroll
    for (int nf = 0; nf < 8; nf++)
      bf[nf] = *(const v4i*)(Bs + (nf * 16 + ln) * 64 + quad * 16);
#pragma unroll
    for (int mt = 0; mt < 2; mt++)
#pragma unroll
      for (int nf = 0; nf < 8; nf++)
        acc[mt][nf] = __builtin_amdgcn_mfma_i32_16x16x64_i8(af[mt], bf[nf], acc[mt][nf], 0, 0, 0);
  }

  const float* s2e = s2w + e * H_DIM;
  float sw[8];
  int ncol[8];
#pragma unroll
  for (int nf = 0; nf < 8; nf++) {
    int n = n0 + nf * 16 + ln;
    ncol[nf] = n;
    sw[nf] = s2e[n];
  }
#pragma unroll
  for (int mt = 0; mt < 2; mt++) {
#pragma unroll
    for (int r = 0; r < 4; r++) {
      int mrel = m0 + wave * 32 + mt * 16 + quad * 4 + r;
      if (mrel >= ce) continue;
      float sa = s_a[offe + mrel];
      float* orow = h2s + (size_t)(offe + mrel) * H_DIM;
#pragma unroll
      for (int nf = 0; nf < 8; nf++)
        orow[ncol[nf]] = (float)acc[mt][nf][r] * sa * sw[nf];
    }
  }
}

// ---------------------------------------------------------------------------
// Final gather: out[t] = g1 * h2s[r1] + g2 * h2s[r2]
// ---------------------------------------------------------------------------
__global__ __launch_bounds__(256) void gather_out(
    const float* __restrict__ h2s, const int* __restrict__ epos,
    const float* __restrict__ gts, const int* __restrict__ off,
    float* __restrict__ out) {
  const int t = blockIdx.x;
  int a = epos[2 * t], b = epos[2 * t + 1];
  float g1 = gts[2 * t], g2 = gts[2 * t + 1];
  int r1 = off[a >> 16] + (a & 0xffff);
  int r2 = off[b >> 16] + (b & 0xffff);
  const float4* R1 = (const float4*)(h2s + (size_t)r1 * H_DIM);
  const float4* R2 = (const float4*)(h2s + (size_t)r2 * H_DIM);
  float4* O = (float4*)(out + (size_t)t * H_DIM);
  for (int c = threadIdx.x; c < H_DIM / 4; c += 256) {
    float4 x = R1[c], y = R2[c];
    float4 z;
    z.x = g1 * x.x + g2 * y.x;
    z.y = g1 * x.y + g2 * y.y;
    z.z = g1 * x.z + g2 * y.z;
    z.w = g1 * x.w + g2 * y.w;
    O[c] = z;
  }
}

// ---------------------------------------------------------------------------
extern "C" void kernel_launch(void* const* d_in, const int* in_sizes, int n_in,
                              void* d_out, int out_size, void* d_ws, size_t ws_size,
                              hipStream_t stream) {
  const float* hs = (const float*)d_in[0];
  const float* gw = (const float*)d_in[1];
  const int* w13 = (const int*)d_in[2];
  const float* s13 = (const float*)d_in[3];
  const int* w2 = (const int*)d_in[4];
  const float* s2w = (const float*)d_in[5];
  float* out = (float*)d_out;

  char* ws = (char*)d_ws;
  size_t o = 0;
  auto take = [&](size_t b) {
    char* p = ws + o;
    o += (b + 255) & ~(size_t)255;
    return p;
  };
  signed char* qw13 = (signed char*)take((size_t)E_NUM * NI2 * H_DIM);       // 46.1 MB
  signed char* qin = (signed char*)take((size_t)T_TOK * H_DIM);              // 8.4 MB
  float* act = (float*)take((size_t)T_TOK * 2 * I_DIM * 4);                  // 46.1 MB
  float* h2s = (float*)qw13;  // aliases dead qw13+qin+act space (67.1 MB needed)
  signed char* qw2 = (signed char*)take((size_t)E_NUM * H_DIM * I_DIM);      // 23.1 MB
  signed char* qa = (signed char*)take((size_t)T_TOK * 2 * I_DIM);           // 11.5 MB
  float* sin_ = (float*)take((size_t)T_TOK * 4);
  float* sa = (float*)take((size_t)T_TOK * 2 * 4);
  unsigned int* amax = (unsigned int*)take((size_t)T_TOK * 2 * 4);
  int* tokl = (int*)take((size_t)E_NUM * T_TOK * 4);
  int* tope = (int*)take((size_t)T_TOK * 2 * 4);
  int* epos = (int*)take((size_t)T_TOK * 2 * 4);
  float* gts = (float*)take((size_t)T_TOK * 2 * 4);
  int* cnt = (int*)take(E_NUM * 4);
  int* off = (int*)take(E_NUM * 4);

  hipMemsetAsync(amax, 0, (size_t)T_TOK * 2 * 4, stream);
  hipMemsetAsync(cnt, 0, (size_t)E_NUM * 4, stream);

  {
    int n16a = E_NUM * NI2 * H_DIM / 16;
    int n16b = E_NUM * H_DIM * I_DIM / 16;
    int n16tot = n16a + n16b;
    pack_all<<<(n16tot + 255) / 256, 256, 0, stream>>>(w13, w2, qw13, qw2, n16a, n16tot);
  }
  gate_route_quant<<<T_TOK, 256, 0, stream>>>(hs, gw, qin, sin_, tope, gts);
  build_lists<<<T_TOK / 256, 256, 0, stream>>>(tope, tokl, epos, cnt);
  calc_off<<<1, 64, 0, stream>>>(cnt, off);
  // 1-D grids: bid = ((xt*32)+yt)*8 + e  (expert = bid&7 -> XCD affinity)
  gemm1_silu<<<(I_DIM / 64) * (T_TOK / 128) * E_NUM, 256, 0, stream>>>(qw13, qin, sin_, s13, tokl, cnt, off, act, amax);
  quant_act<<<T_TOK * 2, 256, 0, stream>>>(act, amax, qa, sa);
  gemm2_h2<<<(H_DIM / 128) * (T_TOK / 128) * E_NUM, 256, 0, stream>>>(qw2, qa, sa, s2w, cnt, off, h2s);
  gather_out<<<T_TOK, 256, 0, stream>>>(h2s, epos, gts, off, out);
}